// Round 3
// baseline (808.998 us; speedup 1.0000x reference)
//
#include <hip/hip_runtime.h>

typedef _Float16 f16;
typedef _Float16 f16x8 __attribute__((ext_vector_type(8)));
typedef float f32x4 __attribute__((ext_vector_type(4)));

static __device__ __forceinline__ f32x4 mfma16(f16x8 a, f16x8 b, f32x4 c) {
  return __builtin_amdgcn_mfma_f32_16x16x32_f16(a, b, c, 0, 0, 0);
}

#define GLD16(gp, lp) __builtin_amdgcn_global_load_lds( \
    (const __attribute__((address_space(1))) unsigned int*)(gp), \
    (__attribute__((address_space(3))) unsigned int*)(lp), 16, 0, 0)

// ---------------- K0: weight prep (fp32 -> f16, transposed to [n][k]) ----------------
__global__ __launch_bounds__(256) void k0_prep(
    const float* __restrict__ W0, const float* __restrict__ b0,
    const float* __restrict__ W1, const float* __restrict__ b1,
    const float* __restrict__ W2, const float* __restrict__ b2,
    const float* __restrict__ W3, const float* __restrict__ b3,
    const float* __restrict__ Wf, const float* __restrict__ Ws,
    f16* __restrict__ wqkvT, f16* __restrict__ wfT, f16* __restrict__ wsT,
    float* __restrict__ bqkv)
{
  int t = blockIdx.x * 256 + threadIdx.x;
  if (t < 49152) {                       // wqkvT [384][128], n = h*96 + j
    int n = t >> 7, k = t & 127;
    int h = n / 96, nn = n - h * 96;
    const float* W = (h == 0) ? W0 : (h == 1) ? W1 : (h == 2) ? W2 : W3;
    wqkvT[t] = (f16)W[k * 96 + nn];
  } else if (t < 114688) {               // wfT [256][256]
    int i = t - 49152;
    int n = i >> 8, k = i & 255;
    wfT[i] = (f16)Wf[k * 256 + n];
  } else if (t < 901120) {               // wsT [256][3072]
    int i = t - 114688;
    int n = i / 3072, k = i - n * 3072;
    wsT[i] = (f16)Ws[k * 256 + n];
  } else if (t < 901504) {               // bqkv [384] fp32
    int i = t - 901120;
    int h = i / 96, j = i - h * 96;
    const float* bp = (h == 0) ? b0 : (h == 1) ? b1 : (h == 2) ? b2 : b3;
    bqkv[i] = bp[j];
  }
}

// ---------------- K1: fused qkv + attention + LN1 + Wf + LN2 -> f_norm (f16) ----------------
// 512 threads (8 waves), 2 blocks/CU -> 16 waves/CU resident (was 8).
#define RB 8            // batch rows per block
#define SR 48           // seq rows = RB*6
#define XP 136          // f16 pitch for 128-col LDS bufs (2-way bank alias only)
#define QP 392          // f16 pitch for qkv (384 cols)
#define NP 264          // f16 pitch for 256-col bufs

__global__ __launch_bounds__(512, 4) void k1_fused(
    const float* __restrict__ x,
    const f16* __restrict__ wqkvT, const f16* __restrict__ wfT,
    const float* __restrict__ bqkv,
    const float* __restrict__ g1, const float* __restrict__ be1,
    const float* __restrict__ bfv,
    const float* __restrict__ g2, const float* __restrict__ be2,
    f16* __restrict__ fbuf)
{
  __shared__ f16 xs[SR * XP];       // x tile (m cols 0..127 / f cols 256..383)
  __shared__ f16 attn[SR * XP];     // attn tile (m cols 128..255 / f cols 384..511)
  __shared__ f16 qn[SR * QP];       // qkv -> n -> nWf (aliased phases)
  __shared__ float cg1[256], cb1[256], cbf[256];
  __shared__ float cg2[512], cb2[512];
  __shared__ float cbq[384];
  __shared__ float sum1[SR], sq1[SR], mu1[SR], rs1[SR];
  __shared__ float sum2[SR], sq2[SR], mu2[SR], rs2[SR];

  const int t = threadIdx.x;
  const int lane = t & 63, wave = t >> 6;   // 8 waves
  const int lr = lane & 15, lq = lane >> 4;
  const int b0r = blockIdx.x * RB;

  // ---- P0: constants + stat zeroing ----
  if (t < 256) { cg1[t] = g1[t]; cb1[t] = be1[t]; cbf[t] = bfv[t]; }
  cg2[t] = g2[t]; cb2[t] = be2[t];
  if (t < 384) cbq[t] = bqkv[t];
  if (t < SR) { sum1[t] = 0.f; sq1[t] = 0.f; sum2[t] = 0.f; sq2[t] = 0.f; }

  // ---- P1: load x -> xs (f16) ----
  {
    const float4* xg = (const float4*)(x + (size_t)b0r * 768);
    #pragma unroll
    for (int it = 0; it < 3; it++) {
      int i = t + it * 512;               // 0..1535 ; 32 float4 per row
      float4 v = xg[i];
      int r = i >> 5, c4 = i & 31;
      f16* d = &xs[r * XP + c4 * 4];
      d[0] = (f16)v.x; d[1] = (f16)v.y; d[2] = (f16)v.z; d[3] = (f16)v.w;
    }
  }
  __syncthreads();

  // ---- P2: qkv = x @ Wqkv + b  (MFMA, M=48 N=384 K=128; 3 n-tiles/wave) ----
  {
    f32x4 acc[3][3];
    #pragma unroll
    for (int mt = 0; mt < 3; mt++)
      #pragma unroll
      for (int nt = 0; nt < 3; nt++) acc[mt][nt] = (f32x4){0.f, 0.f, 0.f, 0.f};
    #pragma unroll
    for (int k0 = 0; k0 < 128; k0 += 32) {
      f16x8 av[3];
      #pragma unroll
      for (int mt = 0; mt < 3; mt++)
        av[mt] = *(const f16x8*)&xs[(mt * 16 + lr) * XP + k0 + lq * 8];
      #pragma unroll
      for (int nt = 0; nt < 3; nt++) {
        int n = (wave * 3 + nt) * 16 + lr;
        f16x8 bv = *(const f16x8*)&wqkvT[n * 128 + k0 + lq * 8];
        #pragma unroll
        for (int mt = 0; mt < 3; mt++) acc[mt][nt] = mfma16(av[mt], bv, acc[mt][nt]);
      }
    }
    #pragma unroll
    for (int mt = 0; mt < 3; mt++)
      #pragma unroll
      for (int nt = 0; nt < 3; nt++) {
        int c = (wave * 3 + nt) * 16 + lr;
        float bb = cbq[c];
        #pragma unroll
        for (int rg = 0; rg < 4; rg++) {
          int r = mt * 16 + lq * 4 + rg;
          qn[r * QP + c] = (f16)(acc[mt][nt][rg] + bb);
        }
      }
  }
  __syncthreads();

  // ---- P3: attention (VALU, fp32 accumulate). thread = (b, h, i) ----
  if (t < 192) {
    int b = t / 24;
    int rem = t - b * 24;
    int h = rem / 6, i = rem - (rem / 6) * 6;
    const f16* base = &qn[(b * 6) * QP + h * 96];
    float q[32], o[32], s[6];
    {
      const f16x8* Qr = (const f16x8*)(base + i * QP);
      #pragma unroll
      for (int u = 0; u < 4; u++) {
        f16x8 v = Qr[u];
        #pragma unroll
        for (int e = 0; e < 8; e++) q[u * 8 + e] = (float)v[e];
      }
    }
    #pragma unroll
    for (int j = 0; j < 6; j++) {
      const f16x8* Kr = (const f16x8*)(base + j * QP + 32);
      float a = 0.f;
      #pragma unroll
      for (int u = 0; u < 4; u++) {
        f16x8 v = Kr[u];
        #pragma unroll
        for (int e = 0; e < 8; e++) a += q[u * 8 + e] * (float)v[e];
      }
      s[j] = a;
    }
    #pragma unroll
    for (int d = 0; d < 32; d++) o[d] = 0.f;
    #pragma unroll
    for (int j = 0; j < 6; j++) {
      const f16x8* Vr = (const f16x8*)(base + j * QP + 64);
      float sj = s[j];
      #pragma unroll
      for (int u = 0; u < 4; u++) {
        f16x8 v = Vr[u];
        #pragma unroll
        for (int e = 0; e < 8; e++) o[u * 8 + e] += sj * (float)v[e];
      }
    }
    f16x8* Ar = (f16x8*)&attn[(b * 6 + i) * XP + h * 32];
    #pragma unroll
    for (int u = 0; u < 4; u++) {
      f16x8 v;
      #pragma unroll
      for (int e = 0; e < 8; e++) v[e] = (f16)o[u * 8 + e];
      Ar[u] = v;
    }
  }
  __syncthreads();

  // ---- P4: LN1 stats over m = [xs | attn] (256 cols); 384 threads, 32 cols each ----
  if (t < 384) {
    int r = t >> 3, qq = t & 7;
    const f16* src = (qq < 4) ? &xs[r * XP + qq * 32] : &attn[r * XP + (qq - 4) * 32];
    float s = 0.f, ss = 0.f;
    #pragma unroll
    for (int u = 0; u < 4; u++) {
      f16x8 v = ((const f16x8*)src)[u];
      #pragma unroll
      for (int e = 0; e < 8; e++) { float f = (float)v[e]; s += f; ss += f * f; }
    }
    atomicAdd(&sum1[r], s);
    atomicAdd(&sq1[r], ss);
  }
  __syncthreads();
  if (t < SR) {
    float mu = sum1[t] * (1.f / 256.f);
    float var = sq1[t] * (1.f / 256.f) - mu * mu;
    mu1[t] = mu; rs1[t] = rsqrtf(var + 1e-5f);
  }
  __syncthreads();

  // ---- P5: n = LN1(m)*g1+be1 -> nbuf (aliases qn; qkv is dead) ----
  f16* nbuf = qn;
  #pragma unroll
  for (int it = 0; it < 2; it++) {
    int i = t + it * 512;                 // 0..767 ; 16 chunks of 16 cols per row
    if (i < 768) {
      int r = i >> 4, cc = i & 15;
      int c0 = cc * 16;
      float mu = mu1[r], rs = rs1[r];
      const f16* src = (c0 < 128) ? &xs[r * XP + c0] : &attn[r * XP + (c0 - 128)];
      f16x8 ov[2];
      #pragma unroll
      for (int u = 0; u < 2; u++) {
        f16x8 v = ((const f16x8*)src)[u];
        #pragma unroll
        for (int e = 0; e < 8; e++) {
          int c = c0 + u * 8 + e;
          ov[u][e] = (f16)(((float)v[e] - mu) * rs * cg1[c] + cb1[c]);
        }
      }
      f16x8* dst = (f16x8*)&nbuf[r * NP + c0];
      dst[0] = ov[0]; dst[1] = ov[1];
    }
  }
  __syncthreads();

  // ---- P6: nWf = n @ Wf (MFMA, M=48 N=256 K=256; 2 n-tiles/wave) ----
  f32x4 facc[3][2];
  #pragma unroll
  for (int mt = 0; mt < 3; mt++)
    #pragma unroll
    for (int nt = 0; nt < 2; nt++) facc[mt][nt] = (f32x4){0.f, 0.f, 0.f, 0.f};
  #pragma unroll
  for (int k0 = 0; k0 < 256; k0 += 32) {
    f16x8 av[3];
    #pragma unroll
    for (int mt = 0; mt < 3; mt++)
      av[mt] = *(const f16x8*)&nbuf[(mt * 16 + lr) * NP + k0 + lq * 8];
    #pragma unroll
    for (int nt = 0; nt < 2; nt++) {
      int n = (wave * 2 + nt) * 16 + lr;
      f16x8 bv = *(const f16x8*)&wfT[n * 256 + k0 + lq * 8];
      #pragma unroll
      for (int mt = 0; mt < 3; mt++) facc[mt][nt] = mfma16(av[mt], bv, facc[mt][nt]);
    }
  }
  __syncthreads();   // all reads of n done; nbuf may be overwritten below

  // ---- P7: add bf, LN2 partial stats (nWf part), write nWf (f16) over nbuf ----
  {
    float vreg[3][2][4];
    #pragma unroll
    for (int mt = 0; mt < 3; mt++)
      #pragma unroll
      for (int nt = 0; nt < 2; nt++) {
        int c = (wave * 2 + nt) * 16 + lr;
        float bb = cbf[c];
        #pragma unroll
        for (int rg = 0; rg < 4; rg++) vreg[mt][nt][rg] = facc[mt][nt][rg] + bb;
      }
    #pragma unroll
    for (int mt = 0; mt < 3; mt++)
      #pragma unroll
      for (int rg = 0; rg < 4; rg++) {
        float s = 0.f, ss = 0.f;
        #pragma unroll
        for (int nt = 0; nt < 2; nt++) { float v = vreg[mt][nt][rg]; s += v; ss += v * v; }
        #pragma unroll
        for (int off = 1; off < 16; off <<= 1) {
          s += __shfl_xor(s, off, 64);
          ss += __shfl_xor(ss, off, 64);
        }
        if (lr == 0) {
          int r = mt * 16 + lq * 4 + rg;
          atomicAdd(&sum2[r], s);
          atomicAdd(&sq2[r], ss);
        }
      }
    #pragma unroll
    for (int mt = 0; mt < 3; mt++)
      #pragma unroll
      for (int nt = 0; nt < 2; nt++) {
        int c = (wave * 2 + nt) * 16 + lr;
        #pragma unroll
        for (int rg = 0; rg < 4; rg++) {
          int r = mt * 16 + lq * 4 + rg;
          nbuf[r * NP + c] = (f16)vreg[mt][nt][rg];
        }
      }
  }
  __syncthreads();
  if (t < SR) {
    float s = sum2[t] + sum1[t];          // m-part stats reused from LN1 raw sums
    float ss = sq2[t] + sq1[t];
    float mu = s * (1.f / 512.f);
    float var = ss * (1.f / 512.f) - mu * mu;
    mu2[t] = mu; rs2[t] = rsqrtf(var + 1e-5f);
  }
  __syncthreads();

  // ---- P8: write f_norm = LN2([nWf | x | attn])*g2+be2 -> fbuf (f16) ----
  {
    f16* fout = fbuf + (size_t)b0r * 3072;
    #pragma unroll
    for (int it = 0; it < 3; it++) {
      int i = t + it * 512;               // 0..1535 ; 32 chunks of 16 per row
      int r = i >> 5, cc = i & 31;
      int c0 = cc * 16;
      float mu = mu2[r], rs = rs2[r];
      const f16* src = (c0 < 256) ? &nbuf[r * NP + c0]
                     : (c0 < 384) ? &xs[r * XP + (c0 - 256)]
                                  : &attn[r * XP + (c0 - 384)];
      f16x8 ov[2];
      #pragma unroll
      for (int u = 0; u < 2; u++) {
        f16x8 v = ((const f16x8*)src)[u];
        #pragma unroll
        for (int e = 0; e < 8; e++) {
          int c = c0 + u * 8 + e;
          ov[u][e] = (f16)(((float)v[e] - mu) * rs * cg2[c] + cb2[c]);
        }
      }
      f16x8* dst = (f16x8*)(fout + (size_t)r * 512 + c0);
      dst[0] = ov[0]; dst[1] = ov[1];
    }
  }
}

// ---------------- K2: out = relu(f @ Ws + bs)  (M=65536 K=3072 N=256) ----------------
// 256x256 tile, BK=64, 8 waves (2M x 4N), double-buffered LDS with 2-phase
// pipeline: stage tile t+1 (global_load_lds w16) overlapped with MFMA on tile t,
// ONE barrier per K-tile. LDS rows are 64 f16 = 128 B (full bank cycle), so
// fragment ds_read_b128 is XOR-swizzled (chunk ^= row&7) via pre-swizzled
// global source addresses (linear LDS dest, per rule: both-sides-or-neither).
__global__ __launch_bounds__(512, 2) void k2_gemm(
    const f16* __restrict__ A, const f16* __restrict__ Bt,
    const float* __restrict__ bs, float* __restrict__ out)
{
  __shared__ __align__(16) f16 As[2 * 256 * 64];   // [buf][row 256][chunk 8][8 f16]
  __shared__ __align__(16) f16 Bs[2 * 256 * 64];
  const int t = threadIdx.x;                // 0..511
  const int l = t & 63, w = t >> 6;         // lane, wave (8 waves)
  const int lr = l & 15, lq = l >> 4;
  const int wm = w >> 2, wn = w & 3;        // 2 x 4 wave grid
  const size_t m0 = (size_t)blockIdx.x * 256;

  // staging: per GLD16 a wave writes 1024 B = 8 rows x 128 B, linear in LDS.
  // lane l covers (row = base+ (l>>3), physical chunk = l&7); the logical
  // k-chunk that belongs there is (l&7) ^ (row&7) = (l&7) ^ (l>>3).
  const int srow = l >> 3;
  const int schk = (l & 7) ^ srow;
  const f16* ap[4]; const f16* bp[4];
  #pragma unroll
  for (int i = 0; i < 4; i++) {
    int r = w * 32 + i * 8 + srow;          // rows 0..255 across 8 waves x 4 issues
    ap[i] = A  + (m0 + r) * 3072 + schk * 8;
    bp[i] = Bt + (size_t)r * 3072 + schk * 8;
  }

  // fragment ds_read offsets (f16 units, without buffer term):
  // row*64 + ((kchunk ^ (row&7)) * 8), kchunk = kk*4 + lq
  int aoff[8][2], boff[4][2];
  #pragma unroll
  for (int mt = 0; mt < 8; mt++)
    #pragma unroll
    for (int kk = 0; kk < 2; kk++) {
      int row = wm * 128 + mt * 16 + lr;
      aoff[mt][kk] = row * 64 + (((kk * 4 + lq) ^ (row & 7)) * 8);
    }
  #pragma unroll
  for (int nt = 0; nt < 4; nt++)
    #pragma unroll
    for (int kk = 0; kk < 2; kk++) {
      int row = wn * 64 + nt * 16 + lr;
      boff[nt][kk] = row * 64 + (((kk * 4 + lq) ^ (row & 7)) * 8);
    }

  f32x4 acc[8][4];
  #pragma unroll
  for (int mt = 0; mt < 8; mt++)
    #pragma unroll
    for (int nt = 0; nt < 4; nt++) acc[mt][nt] = (f32x4){0.f, 0.f, 0.f, 0.f};

  auto stage = [&](int buf, int tile) {
    #pragma unroll
    for (int i = 0; i < 4; i++) {
      GLD16(ap[i] + tile * 64, As + buf * 16384 + w * 2048 + i * 512);
      GLD16(bp[i] + tile * 64, Bs + buf * 16384 + w * 2048 + i * 512);
    }
  };
  auto compute = [&](int buf) {
    #pragma unroll
    for (int kk = 0; kk < 2; kk++) {
      f16x8 av[8], bv[4];
      #pragma unroll
      for (int nt = 0; nt < 4; nt++)
        bv[nt] = *(const f16x8*)&Bs[buf * 16384 + boff[nt][kk]];
      #pragma unroll
      for (int mt = 0; mt < 8; mt++)
        av[mt] = *(const f16x8*)&As[buf * 16384 + aoff[mt][kk]];
      #pragma unroll
      for (int mt = 0; mt < 8; mt++)
        #pragma unroll
        for (int nt = 0; nt < 4; nt++)
          acc[mt][nt] = mfma16(av[mt], bv[nt], acc[mt][nt]);
    }
  };

  // K = 3072 -> 48 tiles of 64. Depth-1 pipeline, one barrier per tile.
  stage(0, 0);
  __syncthreads();                          // drains vmcnt(0): tile 0 ready
  #pragma unroll 1
  for (int kt = 0; kt < 48; kt += 2) {
    stage(1, kt + 1);                       // prefetch next tile (other buffer)
    compute(0);
    __syncthreads();                        // drains stage(1); buf0 reads done
    if (kt + 2 < 48) stage(0, kt + 2);
    compute(1);
    if (kt + 2 < 48) __syncthreads();       // drains stage(0); buf1 reads done
  }

  // epilogue: bias + relu, fp32 store
  #pragma unroll
  for (int nt = 0; nt < 4; nt++) {
    int col = wn * 64 + nt * 16 + lr;
    float bb = bs[col];
    #pragma unroll
    for (int mt = 0; mt < 8; mt++) {
      size_t rowb = m0 + wm * 128 + mt * 16 + lq * 4;
      #pragma unroll
      for (int rg = 0; rg < 4; rg++) {
        float v = acc[mt][nt][rg] + bb;
        out[(rowb + rg) * 256 + col] = v > 0.f ? v : 0.f;
      }
    }
  }
}

// ---------------- launch ----------------
extern "C" void kernel_launch(void* const* d_in, const int* in_sizes, int n_in,
                              void* d_out, int out_size, void* d_ws, size_t ws_size,
                              hipStream_t stream) {
  (void)in_sizes; (void)n_in; (void)out_size; (void)ws_size;
  const float* x   = (const float*)d_in[0];
  const float* W0  = (const float*)d_in[1];  const float* b0  = (const float*)d_in[2];
  const float* W1  = (const float*)d_in[3];  const float* b1  = (const float*)d_in[4];
  const float* W2  = (const float*)d_in[5];  const float* b2  = (const float*)d_in[6];
  const float* W3  = (const float*)d_in[7];  const float* b3  = (const float*)d_in[8];
  const float* g1  = (const float*)d_in[9];  const float* be1 = (const float*)d_in[10];
  const float* Wf  = (const float*)d_in[11]; const float* bf  = (const float*)d_in[12];
  const float* g2  = (const float*)d_in[13]; const float* be2 = (const float*)d_in[14];
  const float* Ws  = (const float*)d_in[15]; const float* bs  = (const float*)d_in[16];
  float* out = (float*)d_out;

  char* ws = (char*)d_ws;
  f16*   wqkvT = (f16*)(ws);                 //   98304 B  [384][128]
  f16*   wfT   = (f16*)(ws + 98304);         //  131072 B  [256][256]
  f16*   wsT   = (f16*)(ws + 229376);        // 1572864 B  [256][3072]
  float* bqkv  = (float*)(ws + 1802240);     //    1536 B
  f16*   fbuf  = (f16*)(ws + 1804288);       // 402653184 B [65536*6][512]

  k0_prep<<<3522, 256, 0, stream>>>(W0, b0, W1, b1, W2, b2, W3, b3, Wf, Ws,
                                    wqkvT, wfT, wsT, bqkv);
  k1_fused<<<8192, 512, 0, stream>>>(x, wqkvT, wfT, bqkv, g1, be1, bf, g2, be2, fbuf);
  k2_gemm<<<256, 512, 0, stream>>>(fbuf, wsT, bs, out);
}

// Round 4
// 730.292 us; speedup vs baseline: 1.1078x; 1.1078x over previous
//
#include <hip/hip_runtime.h>

typedef _Float16 f16;
typedef _Float16 f16x8 __attribute__((ext_vector_type(8)));
typedef float f32x4 __attribute__((ext_vector_type(4)));

static __device__ __forceinline__ f32x4 mfma16(f16x8 a, f16x8 b, f32x4 c) {
  return __builtin_amdgcn_mfma_f32_16x16x32_f16(a, b, c, 0, 0, 0);
}

#define GLD16(gp, lp) __builtin_amdgcn_global_load_lds( \
    (const __attribute__((address_space(1))) unsigned int*)(gp), \
    (__attribute__((address_space(3))) unsigned int*)(lp), 16, 0, 0)

// ---------------- K0: weight prep (fp32 -> f16, transposed to [n][k]) ----------------
__global__ __launch_bounds__(256) void k0_prep(
    const float* __restrict__ W0, const float* __restrict__ b0,
    const float* __restrict__ W1, const float* __restrict__ b1,
    const float* __restrict__ W2, const float* __restrict__ b2,
    const float* __restrict__ W3, const float* __restrict__ b3,
    const float* __restrict__ Wf, const float* __restrict__ Ws,
    f16* __restrict__ wqkvT, f16* __restrict__ wfT, f16* __restrict__ wsT,
    float* __restrict__ bqkv)
{
  int t = blockIdx.x * 256 + threadIdx.x;
  if (t < 49152) {                       // wqkvT [384][128], n = h*96 + j
    int n = t >> 7, k = t & 127;
    int h = n / 96, nn = n - h * 96;
    const float* W = (h == 0) ? W0 : (h == 1) ? W1 : (h == 2) ? W2 : W3;
    wqkvT[t] = (f16)W[k * 96 + nn];
  } else if (t < 114688) {               // wfT [256][256]
    int i = t - 49152;
    int n = i >> 8, k = i & 255;
    wfT[i] = (f16)Wf[k * 256 + n];
  } else if (t < 901120) {               // wsT [256][3072]
    int i = t - 114688;
    int n = i / 3072, k = i - n * 3072;
    wsT[i] = (f16)Ws[k * 256 + n];
  } else if (t < 901504) {               // bqkv [384] fp32
    int i = t - 901120;
    int h = i / 96, j = i - h * 96;
    const float* bp = (h == 0) ? b0 : (h == 1) ? b1 : (h == 2) ? b2 : b3;
    bqkv[i] = bp[j];
  }
}

// ---------------- K1: fused qkv + attention + LN1 + Wf + LN2 -> f_norm (f16) ----------------
// 256 threads, LDS = 51 KB -> 3 blocks/CU (12 waves/CU). Constants read from
// global (L2-hot). attn output lives in qn's Q columns; n and nWf live in
// qn's dead K/V bands (cols 32+band*96, band=c>>6).
#define RB 8            // batch rows per block
#define SR 48           // seq rows = RB*6
#define XP 136          // f16 pitch for 128-col x tile
#define QP 392          // f16 pitch for qkv (384 cols)

__global__ __launch_bounds__(256, 3) void k1_fused(
    const float* __restrict__ x,
    const f16* __restrict__ wqkvT, const f16* __restrict__ wfT,
    const float* __restrict__ bqkv,
    const float* __restrict__ g1, const float* __restrict__ be1,
    const float* __restrict__ bfv,
    const float* __restrict__ g2, const float* __restrict__ be2,
    f16* __restrict__ fbuf)
{
  __shared__ f16 xs[SR * XP];       // x tile (m cols 0..127 / f cols 256..383)
  __shared__ f16 qn[SR * QP];       // qkv; Q cols -> attn; K/V bands -> n -> nWf
  __shared__ float sum1[SR], sq1[SR], mu1[SR], rs1[SR];
  __shared__ float sum2[SR], sq2[SR], mu2[SR], rs2[SR];

  const int t = threadIdx.x;
  const int lane = t & 63, wave = t >> 6;   // 4 waves
  const int lr = lane & 15, lq = lane >> 4;
  const int b0r = blockIdx.x * RB;

  // ---- P0: stat zeroing ----
  if (t < SR) { sum1[t] = 0.f; sq1[t] = 0.f; sum2[t] = 0.f; sq2[t] = 0.f; }

  // ---- P1: load x -> xs (f16) ----
  {
    const float4* xg = (const float4*)(x + (size_t)b0r * 768);
    #pragma unroll
    for (int it = 0; it < 6; it++) {
      int i = t + it * 256;               // 0..1535 ; 32 float4 per row
      float4 v = xg[i];
      int r = i >> 5, c4 = i & 31;
      f16* d = &xs[r * XP + c4 * 4];
      d[0] = (f16)v.x; d[1] = (f16)v.y; d[2] = (f16)v.z; d[3] = (f16)v.w;
    }
  }
  __syncthreads();

  // ---- P2: qkv = x @ Wqkv + b  (MFMA, M=48 N=384 K=128; 6 n-tiles/wave) ----
  {
    f32x4 acc[3][6];
    #pragma unroll
    for (int mt = 0; mt < 3; mt++)
      #pragma unroll
      for (int nt = 0; nt < 6; nt++) acc[mt][nt] = (f32x4){0.f, 0.f, 0.f, 0.f};
    #pragma unroll
    for (int k0 = 0; k0 < 128; k0 += 32) {
      f16x8 av[3];
      #pragma unroll
      for (int mt = 0; mt < 3; mt++)
        av[mt] = *(const f16x8*)&xs[(mt * 16 + lr) * XP + k0 + lq * 8];
      #pragma unroll
      for (int nt = 0; nt < 6; nt++) {
        int n = (wave * 6 + nt) * 16 + lr;
        f16x8 bv = *(const f16x8*)&wqkvT[n * 128 + k0 + lq * 8];
        #pragma unroll
        for (int mt = 0; mt < 3; mt++) acc[mt][nt] = mfma16(av[mt], bv, acc[mt][nt]);
      }
    }
    #pragma unroll
    for (int nt = 0; nt < 6; nt++) {
      int c = (wave * 6 + nt) * 16 + lr;
      float bb = bqkv[c];                 // global, L2-hot
      #pragma unroll
      for (int mt = 0; mt < 3; mt++) {
        #pragma unroll
        for (int rg = 0; rg < 4; rg++) {
          int r = mt * 16 + lq * 4 + rg;
          qn[r * QP + c] = (f16)(acc[mt][nt][rg] + bb);
        }
      }
    }
  }
  __syncthreads();

  // ---- P3: attention (VALU, fp32 accumulate). thread = (b, h, i).
  //      Output overwrites own Q band (cols h*96..h*96+31) -- race-free:
  //      Q row i is read only by thread (b,h,i), which has it in regs. ----
  if (t < 192) {
    int b = t / 24;
    int rem = t - b * 24;
    int h = rem / 6, i = rem - (rem / 6) * 6;
    const f16* base = &qn[(b * 6) * QP + h * 96];
    float q[32], o[32], s[6];
    {
      const f16x8* Qr = (const f16x8*)(base + i * QP);
      #pragma unroll
      for (int u = 0; u < 4; u++) {
        f16x8 v = Qr[u];
        #pragma unroll
        for (int e = 0; e < 8; e++) q[u * 8 + e] = (float)v[e];
      }
    }
    #pragma unroll
    for (int j = 0; j < 6; j++) {
      const f16x8* Kr = (const f16x8*)(base + j * QP + 32);
      float a = 0.f;
      #pragma unroll
      for (int u = 0; u < 4; u++) {
        f16x8 v = Kr[u];
        #pragma unroll
        for (int e = 0; e < 8; e++) a += q[u * 8 + e] * (float)v[e];
      }
      s[j] = a;
    }
    #pragma unroll
    for (int d = 0; d < 32; d++) o[d] = 0.f;
    #pragma unroll
    for (int j = 0; j < 6; j++) {
      const f16x8* Vr = (const f16x8*)(base + j * QP + 64);
      float sj = s[j];
      #pragma unroll
      for (int u = 0; u < 4; u++) {
        f16x8 v = Vr[u];
        #pragma unroll
        for (int e = 0; e < 8; e++) o[u * 8 + e] += sj * (float)v[e];
      }
    }
    f16x8* Ar = (f16x8*)&qn[(b * 6 + i) * QP + h * 96];   // overwrite own Q band
    #pragma unroll
    for (int u = 0; u < 4; u++) {
      f16x8 v;
      #pragma unroll
      for (int e = 0; e < 8; e++) v[e] = (f16)o[u * 8 + e];
      Ar[u] = v;
    }
  }
  __syncthreads();

  // ---- P4: LN1 stats over m = [xs | attn(Q bands)] (256 cols) ----
  if (t < 192) {
    int r = t >> 2, qq = t & 3;
    float s = 0.f, ss = 0.f;
    if (qq < 2) {
      const f16x8* src = (const f16x8*)&xs[r * XP + qq * 64];
      #pragma unroll
      for (int u = 0; u < 8; u++) {
        f16x8 v = src[u];
        #pragma unroll
        for (int e = 0; e < 8; e++) { float f = (float)v[e]; s += f; ss += f * f; }
      }
    } else {
      int h0 = (qq - 2) * 2;              // heads h0, h0+1 (32 cols each)
      const f16x8* s0 = (const f16x8*)&qn[r * QP + h0 * 96];
      const f16x8* s1 = (const f16x8*)&qn[r * QP + (h0 + 1) * 96];
      #pragma unroll
      for (int u = 0; u < 4; u++) {
        f16x8 v = s0[u];
        #pragma unroll
        for (int e = 0; e < 8; e++) { float f = (float)v[e]; s += f; ss += f * f; }
      }
      #pragma unroll
      for (int u = 0; u < 4; u++) {
        f16x8 v = s1[u];
        #pragma unroll
        for (int e = 0; e < 8; e++) { float f = (float)v[e]; s += f; ss += f * f; }
      }
    }
    atomicAdd(&sum1[r], s);
    atomicAdd(&sq1[r], ss);
  }
  __syncthreads();
  if (t < SR) {
    float mu = sum1[t] * (1.f / 256.f);
    float var = sq1[t] * (1.f / 256.f) - mu * mu;
    mu1[t] = mu; rs1[t] = rsqrtf(var + 1e-5f);
  }
  __syncthreads();

  // ---- P5: n = LN1(m)*g1+be1 -> K/V bands of qn (band = c0>>6, at 32+band*96) ----
  #pragma unroll
  for (int it = 0; it < 3; it++) {
    int i = t + it * 256;                 // 0..767 ; 16 chunks of 16 cols per row
    int r = i >> 4, cc = i & 15;
    int c0 = cc * 16;
    float mu = mu1[r], rs = rs1[r];
    const f16* src = (c0 < 128)
        ? &xs[r * XP + c0]
        : &qn[r * QP + ((c0 - 128) >> 5) * 96 + ((c0 - 128) & 31)];
    const float4* G = (const float4*)(g1 + c0);
    const float4* Bz = (const float4*)(be1 + c0);
    float gv[16], bv[16];
    #pragma unroll
    for (int u = 0; u < 4; u++) {
      float4 a = G[u], b = Bz[u];
      gv[u*4+0]=a.x; gv[u*4+1]=a.y; gv[u*4+2]=a.z; gv[u*4+3]=a.w;
      bv[u*4+0]=b.x; bv[u*4+1]=b.y; bv[u*4+2]=b.z; bv[u*4+3]=b.w;
    }
    f16x8 ov[2];
    #pragma unroll
    for (int u = 0; u < 2; u++) {
      f16x8 v = ((const f16x8*)src)[u];
      #pragma unroll
      for (int e = 0; e < 8; e++) {
        int idx = u * 8 + e;
        ov[u][e] = (f16)(((float)v[e] - mu) * rs * gv[idx] + bv[idx]);
      }
    }
    f16x8* dst = (f16x8*)&qn[r * QP + 32 + (c0 >> 6) * 96 + (c0 & 63)];
    dst[0] = ov[0]; dst[1] = ov[1];
  }
  __syncthreads();

  // ---- P6: nWf = n @ Wf (MFMA, M=48 N=256 K=256; 4 n-tiles/wave) ----
  f32x4 facc[3][4];
  #pragma unroll
  for (int mt = 0; mt < 3; mt++)
    #pragma unroll
    for (int nt = 0; nt < 4; nt++) facc[mt][nt] = (f32x4){0.f, 0.f, 0.f, 0.f};
  #pragma unroll
  for (int k0 = 0; k0 < 256; k0 += 32) {
    int nband = k0 >> 6, noff = (k0 & 63) + lq * 8;   // 8-chunks stay in-band
    f16x8 av[3];
    #pragma unroll
    for (int mt = 0; mt < 3; mt++)
      av[mt] = *(const f16x8*)&qn[(mt * 16 + lr) * QP + 32 + nband * 96 + noff];
    #pragma unroll
    for (int nt = 0; nt < 4; nt++) {
      int n = (wave * 4 + nt) * 16 + lr;
      f16x8 bv = *(const f16x8*)&wfT[n * 256 + k0 + lq * 8];
      #pragma unroll
      for (int mt = 0; mt < 3; mt++) facc[mt][nt] = mfma16(av[mt], bv, facc[mt][nt]);
    }
  }
  __syncthreads();   // all reads of n done; K/V bands may be overwritten below

  // ---- P7: add bf, LN2 partial stats (nWf part), write nWf over K/V bands ----
  {
    float vreg[3][4][4];
    #pragma unroll
    for (int nt = 0; nt < 4; nt++) {
      int c = (wave * 4 + nt) * 16 + lr;
      float bb = bfv[c];                  // global, L2-hot
      #pragma unroll
      for (int mt = 0; mt < 3; mt++)
        #pragma unroll
        for (int rg = 0; rg < 4; rg++) vreg[mt][nt][rg] = facc[mt][nt][rg] + bb;
    }
    #pragma unroll
    for (int mt = 0; mt < 3; mt++)
      #pragma unroll
      for (int rg = 0; rg < 4; rg++) {
        float s = 0.f, ss = 0.f;
        #pragma unroll
        for (int nt = 0; nt < 4; nt++) { float v = vreg[mt][nt][rg]; s += v; ss += v * v; }
        #pragma unroll
        for (int off = 1; off < 16; off <<= 1) {
          s += __shfl_xor(s, off, 64);
          ss += __shfl_xor(ss, off, 64);
        }
        if (lr == 0) {
          int r = mt * 16 + lq * 4 + rg;
          atomicAdd(&sum2[r], s);
          atomicAdd(&sq2[r], ss);
        }
      }
    #pragma unroll
    for (int mt = 0; mt < 3; mt++)
      #pragma unroll
      for (int nt = 0; nt < 4; nt++) {
        int c = (wave * 4 + nt) * 16 + lr;
        int cb = 32 + (c >> 6) * 96 + (c & 63);
        #pragma unroll
        for (int rg = 0; rg < 4; rg++) {
          int r = mt * 16 + lq * 4 + rg;
          qn[r * QP + cb] = (f16)vreg[mt][nt][rg];
        }
      }
  }
  __syncthreads();
  if (t < SR) {
    float s = sum2[t] + sum1[t];          // m-part stats reused from LN1 raw sums
    float ss = sq2[t] + sq1[t];
    float mu = s * (1.f / 512.f);
    float var = ss * (1.f / 512.f) - mu * mu;
    mu2[t] = mu; rs2[t] = rsqrtf(var + 1e-5f);
  }
  __syncthreads();

  // ---- P8: write f_norm = LN2([nWf | x | attn])*g2+be2 -> fbuf (f16) ----
  {
    f16* fout = fbuf + (size_t)b0r * 3072;
    #pragma unroll
    for (int it = 0; it < 6; it++) {
      int i = t + it * 256;               // 0..1535 ; 32 chunks of 16 per row
      int r = i >> 5, cc = i & 31;
      int c0 = cc * 16;
      float mu = mu2[r], rs = rs2[r];
      const f16* src = (c0 < 256)
          ? &qn[r * QP + 32 + (c0 >> 6) * 96 + (c0 & 63)]                 // nWf bands
          : (c0 < 384)
          ? &xs[r * XP + (c0 - 256)]                                       // x
          : &qn[r * QP + ((c0 - 384) >> 5) * 96 + ((c0 - 384) & 31)];      // attn (Q bands)
      const float4* G = (const float4*)(g2 + c0);
      const float4* Bz = (const float4*)(be2 + c0);
      float gv[16], bv[16];
      #pragma unroll
      for (int u = 0; u < 4; u++) {
        float4 a = G[u], b = Bz[u];
        gv[u*4+0]=a.x; gv[u*4+1]=a.y; gv[u*4+2]=a.z; gv[u*4+3]=a.w;
        bv[u*4+0]=b.x; bv[u*4+1]=b.y; bv[u*4+2]=b.z; bv[u*4+3]=b.w;
      }
      f16x8 ov[2];
      #pragma unroll
      for (int u = 0; u < 2; u++) {
        f16x8 v = ((const f16x8*)src)[u];
        #pragma unroll
        for (int e = 0; e < 8; e++) {
          int idx = u * 8 + e;
          ov[u][e] = (f16)(((float)v[e] - mu) * rs * gv[idx] + bv[idx]);
        }
      }
      f16x8* dst = (f16x8*)(fout + (size_t)r * 512 + c0);
      dst[0] = ov[0]; dst[1] = ov[1];
    }
  }
}

// ---------------- K2: out = relu(f @ Ws + bs)  (M=65536 K=3072 N=256) ----------------
__global__ __launch_bounds__(512, 2) void k2_gemm(
    const f16* __restrict__ A, const f16* __restrict__ Bt,
    const float* __restrict__ bs, float* __restrict__ out)
{
  __shared__ __align__(16) f16 As[2 * 256 * 64];   // [buf][row 256][chunk 8][8 f16]
  __shared__ __align__(16) f16 Bs[2 * 256 * 64];
  const int t = threadIdx.x;                // 0..511
  const int l = t & 63, w = t >> 6;         // lane, wave (8 waves)
  const int lr = l & 15, lq = l >> 4;
  const int wm = w >> 2, wn = w & 3;        // 2 x 4 wave grid
  const size_t m0 = (size_t)blockIdx.x * 256;

  const int srow = l >> 3;
  const int schk = (l & 7) ^ srow;
  const f16* ap[4]; const f16* bp[4];
  #pragma unroll
  for (int i = 0; i < 4; i++) {
    int r = w * 32 + i * 8 + srow;          // rows 0..255 across 8 waves x 4 issues
    ap[i] = A  + (m0 + r) * 3072 + schk * 8;
    bp[i] = Bt + (size_t)r * 3072 + schk * 8;
  }

  int aoff[8][2], boff[4][2];
  #pragma unroll
  for (int mt = 0; mt < 8; mt++)
    #pragma unroll
    for (int kk = 0; kk < 2; kk++) {
      int row = wm * 128 + mt * 16 + lr;
      aoff[mt][kk] = row * 64 + (((kk * 4 + lq) ^ (row & 7)) * 8);
    }
  #pragma unroll
  for (int nt = 0; nt < 4; nt++)
    #pragma unroll
    for (int kk = 0; kk < 2; kk++) {
      int row = wn * 64 + nt * 16 + lr;
      boff[nt][kk] = row * 64 + (((kk * 4 + lq) ^ (row & 7)) * 8);
    }

  f32x4 acc[8][4];
  #pragma unroll
  for (int mt = 0; mt < 8; mt++)
    #pragma unroll
    for (int nt = 0; nt < 4; nt++) acc[mt][nt] = (f32x4){0.f, 0.f, 0.f, 0.f};

  auto stage = [&](int buf, int tile) {
    #pragma unroll
    for (int i = 0; i < 4; i++) {
      GLD16(ap[i] + tile * 64, As + buf * 16384 + w * 2048 + i * 512);
      GLD16(bp[i] + tile * 64, Bs + buf * 16384 + w * 2048 + i * 512);
    }
  };
  auto compute = [&](int buf) {
    #pragma unroll
    for (int kk = 0; kk < 2; kk++) {
      f16x8 av[8], bv[4];
      #pragma unroll
      for (int nt = 0; nt < 4; nt++)
        bv[nt] = *(const f16x8*)&Bs[buf * 16384 + boff[nt][kk]];
      #pragma unroll
      for (int mt = 0; mt < 8; mt++)
        av[mt] = *(const f16x8*)&As[buf * 16384 + aoff[mt][kk]];
      #pragma unroll
      for (int mt = 0; mt < 8; mt++)
        #pragma unroll
        for (int nt = 0; nt < 4; nt++)
          acc[mt][nt] = mfma16(av[mt], bv[nt], acc[mt][nt]);
    }
  };

  stage(0, 0);
  __syncthreads();                          // drains vmcnt(0): tile 0 ready
  #pragma unroll 1
  for (int kt = 0; kt < 48; kt += 2) {
    stage(1, kt + 1);                       // prefetch next tile (other buffer)
    compute(0);
    __syncthreads();                        // drains stage(1); buf0 reads done
    if (kt + 2 < 48) stage(0, kt + 2);
    compute(1);
    if (kt + 2 < 48) __syncthreads();       // drains stage(0); buf1 reads done
  }

  // epilogue: bias + relu, fp32 store
  #pragma unroll
  for (int nt = 0; nt < 4; nt++) {
    int col = wn * 64 + nt * 16 + lr;
    float bb = bs[col];
    #pragma unroll
    for (int mt = 0; mt < 8; mt++) {
      size_t rowb = m0 + wm * 128 + mt * 16 + lq * 4;
      #pragma unroll
      for (int rg = 0; rg < 4; rg++) {
        float v = acc[mt][nt][rg] + bb;
        out[(rowb + rg) * 256 + col] = v > 0.f ? v : 0.f;
      }
    }
  }
}

// ---------------- launch ----------------
extern "C" void kernel_launch(void* const* d_in, const int* in_sizes, int n_in,
                              void* d_out, int out_size, void* d_ws, size_t ws_size,
                              hipStream_t stream) {
  (void)in_sizes; (void)n_in; (void)out_size; (void)ws_size;
  const float* x   = (const float*)d_in[0];
  const float* W0  = (const float*)d_in[1];  const float* b0  = (const float*)d_in[2];
  const float* W1  = (const float*)d_in[3];  const float* b1  = (const float*)d_in[4];
  const float* W2  = (const float*)d_in[5];  const float* b2  = (const float*)d_in[6];
  const float* W3  = (const float*)d_in[7];  const float* b3  = (const float*)d_in[8];
  const float* g1  = (const float*)d_in[9];  const float* be1 = (const float*)d_in[10];
  const float* Wf  = (const float*)d_in[11]; const float* bf  = (const float*)d_in[12];
  const float* g2  = (const float*)d_in[13]; const float* be2 = (const float*)d_in[14];
  const float* Ws  = (const float*)d_in[15]; const float* bs  = (const float*)d_in[16];
  float* out = (float*)d_out;

  char* ws = (char*)d_ws;
  f16*   wqkvT = (f16*)(ws);                 //   98304 B  [384][128]
  f16*   wfT   = (f16*)(ws + 98304);         //  131072 B  [256][256]
  f16*   wsT   = (f16*)(ws + 229376);        // 1572864 B  [256][3072]
  float* bqkv  = (float*)(ws + 1802240);     //    1536 B
  f16*   fbuf  = (f16*)(ws + 1804288);       // 402653184 B [65536*6][512]

  k0_prep<<<3522, 256, 0, stream>>>(W0, b0, W1, b1, W2, b2, W3, b3, Wf, Ws,
                                    wqkvT, wfT, wsT, bqkv);
  k1_fused<<<8192, 256, 0, stream>>>(x, wqkvT, wfT, bqkv, g1, be1, bf, g2, be2, fbuf);
  k2_gemm<<<256, 512, 0, stream>>>(fbuf, wsT, bs, out);
}